// Round 6
// baseline (248.954 us; speedup 1.0000x reference)
//
#include <hip/hip_runtime.h>
#include <cstdint>
#include <cstddef>

typedef unsigned short u16;
typedef __attribute__((ext_vector_type(8))) short bf16x8;   // 8 bf16 = 4 VGPRs
typedef __attribute__((ext_vector_type(4))) float f32x4;

__device__ __forceinline__ u16 f2bf(float f) {
  unsigned u = __builtin_bit_cast(unsigned, f);
  return (u16)((u + 0x7FFFu + ((u >> 16) & 1u)) >> 16);   // RNE
}

__device__ __forceinline__ void gload_lds16(const void* g, void* l) {
  __builtin_amdgcn_global_load_lds(
      (const __attribute__((address_space(1))) void*)g,
      (__attribute__((address_space(3))) void*)l,
      16, 0, 0);
}

// ---------------- merged cast fp32 -> bf16 (x + 4 weights, one launch) ----------------
__global__ void cast_all_kernel(const float* __restrict__ x,
                                const float* __restrict__ wq, const float* __restrict__ wk,
                                const float* __restrict__ wv, const float* __restrict__ wo,
                                u16* __restrict__ ox,
                                u16* __restrict__ oq, u16* __restrict__ ok,
                                u16* __restrict__ ov, u16* __restrict__ oo) {
  const int which = blockIdx.y;
  const float* in = which == 0 ? x  : which == 1 ? wq : which == 2 ? wk
                                    : which == 3 ? wv : wo;
  u16* out        = which == 0 ? ox : which == 1 ? oq : which == 2 ? ok
                                    : which == 3 ? ov : oo;
  const int n4 = which == 0 ? 8192 * 1024 / 4 : 262144;
  int i = blockIdx.x * blockDim.x + threadIdx.x;
  int stride = gridDim.x * blockDim.x;
  for (int idx = i; idx < n4; idx += stride) {
    float4 f = ((const float4*)in)[idx];
    ushort4 o = make_ushort4(f2bf(f.x), f2bf(f.y), f2bf(f.z), f2bf(f.w));
    ((ushort4*)out)[idx] = o;
  }
}

// ================= fused QKV GEMM, 8-phase 256x256 / BK=64 / 8-wave =================
// A (8192x1024) x W_qkv^T (3072x1024). Output per 1024-wide n-region:
// Q row-major, K row-major, V transposed (B,H,dk,S).
// LDS: 2 dbuf x (A 256x64 + B 256x64) bf16 = 128 KiB.
// Swizzle: LDS chunk c (16B units, 8/row) holds global chunk c ^ (row&7);
// achieved via inverse-swizzled GLOBAL source + swizzled ds_read (linear LDS dest).
// vmcnt(4) only at phases 4 and 8 (2 loads/wave/phase; 12 in flight -> drain to 4).

#define STAGE_A8(BUF, H, T)                                                    \
  { const u16* s_ = Asrc + (size_t)(H) * 131072 + (T) * 64;                    \
    u16* d_ = &lds[(BUF) * 32768 + (H) * 8192 + wid * 512];                    \
    gload_lds16(s_, d_);                                                       \
    gload_lds16(s_ + 65536, d_ + 4096); }

#define STAGE_B8(BUF, H, T)                                                    \
  { const u16* s_ = Wsrc + (size_t)(H) * 131072 + (T) * 64;                    \
    u16* d_ = &lds[(BUF) * 32768 + 16384 + (H) * 8192 + wid * 512];            \
    gload_lds16(s_, d_);                                                       \
    gload_lds16(s_ + 65536, d_ + 4096); }

#define LOAD_A8(BUF, MH)                                                       \
  _Pragma("unroll") for (int j_ = 0; j_ < 4; ++j_) {                           \
    const int r_ = ((MH) * 4 + j_) * 16 + lc;                                  \
    const int o_ = (BUF) * 32768 + abase + r_ * 64;                            \
    a[j_][0] = *(const bf16x8*)&lds[o_ + ((g ^ (r_ & 7)) * 8)];                \
    a[j_][1] = *(const bf16x8*)&lds[o_ + (((4 + g) ^ (r_ & 7)) * 8)];          \
  }

#define LOAD_B8(BUF, NH, BREG)                                                 \
  _Pragma("unroll") for (int j_ = 0; j_ < 2; ++j_) {                           \
    const int r_ = brlo + ((NH) * 2 + j_) * 16 + lc;                           \
    const int o_ = (BUF) * 32768 + bbase + r_ * 64;                            \
    BREG[j_][0] = *(const bf16x8*)&lds[o_ + ((g ^ (r_ & 7)) * 8)];             \
    BREG[j_][1] = *(const bf16x8*)&lds[o_ + (((4 + g) ^ (r_ & 7)) * 8)];       \
  }

#define MMAQ8(MH, NH, BREG)                                                    \
  __builtin_amdgcn_s_setprio(1);                                               \
  _Pragma("unroll") for (int j_ = 0; j_ < 4; ++j_)                             \
    _Pragma("unroll") for (int n_ = 0; n_ < 2; ++n_) {                         \
      acc[(MH) * 4 + j_][(NH) * 2 + n_] =                                      \
          __builtin_amdgcn_mfma_f32_16x16x32_bf16(                             \
              a[j_][0], BREG[n_][0], acc[(MH) * 4 + j_][(NH) * 2 + n_], 0, 0, 0); \
      acc[(MH) * 4 + j_][(NH) * 2 + n_] =                                      \
          __builtin_amdgcn_mfma_f32_16x16x32_bf16(                             \
              a[j_][1], BREG[n_][1], acc[(MH) * 4 + j_][(NH) * 2 + n_], 0, 0, 0); \
    }                                                                          \
  __builtin_amdgcn_s_setprio(0);

#define BAR1a                                                                  \
  __builtin_amdgcn_s_barrier();                                                \
  asm volatile("s_waitcnt lgkmcnt(0)" ::: "memory");                           \
  __builtin_amdgcn_sched_barrier(0);

#define BAR2a __builtin_amdgcn_s_barrier();

#define VMW(N) asm volatile("s_waitcnt vmcnt(" #N ")" ::: "memory");

__global__ __launch_bounds__(512, 2)
void gemm_qkv8(const u16* __restrict__ A, const u16* __restrict__ W,
               const float* __restrict__ bq, const float* __restrict__ bk,
               const float* __restrict__ bvv,
               u16* __restrict__ qout, u16* __restrict__ kout, u16* __restrict__ vt) {
  __shared__ u16 lds[65536];   // 128 KiB
  const int tid  = threadIdx.x;
  const int lane = tid & 63;
  const int wid  = tid >> 6;       // 0..7
  const int wr   = wid >> 2;       // 0..1 : which 128-row half of C
  const int wc   = wid & 3;        // 0..3 : which 64-col strip of C
  const int lc   = lane & 15;
  const int g    = lane >> 4;

  // XCD-bijective swizzle: 384 = 8 x 48; m-major within XCD for A-panel L2 reuse
  const int orig = blockIdx.x;
  const int swz  = (orig & 7) * 48 + (orig >> 3);
  const int m0 = (swz / 12) * 256;
  const int n0 = (swz % 12) * 256;

  // staging: thread covers 16B-chunks tid and tid+512 of each 128x64 half-tile
  const int srow  = tid >> 3;                         // 0..63
  const int scol8 = ((tid & 7) ^ (srow & 7)) * 8;     // inverse-swizzled source col
  const u16* Asrc = A + (size_t)(m0 + srow) * 1024 + scol8;
  const u16* Wsrc = W + (size_t)(n0 + srow) * 1024 + scol8;

  const int abase = wr * 8192;                 // + BUF*32768
  const int bbase = 16384 + (wc >> 1) * 8192;  // + BUF*32768
  const int brlo  = (wc & 1) * 64;

  f32x4 acc[8][4] = {};
  bf16x8 a[4][2], bA[2][2], bB[2][2];

  // ---- prologue: tile0 full -> buf0 ; tile1 B -> buf1 ----
  STAGE_B8(0, 0, 0) STAGE_B8(0, 1, 0) STAGE_A8(0, 0, 0) STAGE_A8(0, 1, 0)
  STAGE_B8(1, 0, 1) STAGE_B8(1, 1, 1)
  VMW(4)
  __builtin_amdgcn_s_barrier();

  // ---- main loop: iteration i computes tiles 2i (buf0), 2i+1 (buf1) ----
  for (int i = 0; i < 7; ++i) {
    const int tb  = 2 * i + 1;
    const int ta2 = 2 * i + 2;
    const int tb2 = 2 * i + 3;
    // Ph1: buf0 quad(0,0); stage buf1.Ah0 (tile 2i+1)
    LOAD_A8(0, 0) LOAD_B8(0, 0, bA) STAGE_A8(1, 0, tb) BAR1a MMAQ8(0, 0, bA) BAR2a
    // Ph2: buf0 quad(0,1); stage buf1.Ah1
    LOAD_B8(0, 1, bB) STAGE_A8(1, 1, tb) BAR1a MMAQ8(0, 1, bB) BAR2a
    // Ph3: buf0 quad(1,0); stage buf0.Bh0 (tile 2i+2)
    LOAD_A8(0, 1) STAGE_B8(0, 0, ta2) BAR1a MMAQ8(1, 0, bA) BAR2a
    // Ph4: buf0 quad(1,1); stage buf0.Bh1; counted vmcnt
    STAGE_B8(0, 1, ta2) BAR1a MMAQ8(1, 1, bB) VMW(4) BAR2a
    // Ph5: buf1 quad(0,0); stage buf0.Ah0 (tile 2i+2)
    LOAD_A8(1, 0) LOAD_B8(1, 0, bA) STAGE_A8(0, 0, ta2) BAR1a MMAQ8(0, 0, bA) BAR2a
    // Ph6: buf1 quad(0,1); stage buf0.Ah1
    LOAD_B8(1, 1, bB) STAGE_A8(0, 1, ta2) BAR1a MMAQ8(0, 1, bB) BAR2a
    // Ph7: buf1 quad(1,0); stage buf1.Bh0 (tile 2i+3)
    LOAD_A8(1, 1) STAGE_B8(1, 0, tb2) BAR1a MMAQ8(1, 0, bA) BAR2a
    // Ph8: buf1 quad(1,1); stage buf1.Bh1; counted vmcnt
    STAGE_B8(1, 1, tb2) BAR1a MMAQ8(1, 1, bB) VMW(4) BAR2a
  }
  // ---- epilogue iteration: tiles 14 (buf0), 15 (buf1) ----
  LOAD_A8(0, 0) LOAD_B8(0, 0, bA) STAGE_A8(1, 0, 15) BAR1a MMAQ8(0, 0, bA) BAR2a
  LOAD_B8(0, 1, bB) STAGE_A8(1, 1, 15) BAR1a MMAQ8(0, 1, bB) BAR2a
  LOAD_A8(0, 1) BAR1a MMAQ8(1, 0, bA) BAR2a
  BAR1a MMAQ8(1, 1, bB) VMW(0) BAR2a
  LOAD_A8(1, 0) LOAD_B8(1, 0, bA) BAR1a MMAQ8(0, 0, bA) BAR2a
  LOAD_B8(1, 1, bB) BAR1a MMAQ8(0, 1, bB) BAR2a
  LOAD_A8(1, 1) BAR1a MMAQ8(1, 0, bA) BAR2a
  BAR1a MMAQ8(1, 1, bB)

  // ---- C write: row = m0 + wr*128 + mi*16 + g*4 + r ; col = n0 + wc*64 + ni*16 + lc
  const int region = n0 >> 10;   // 0=Q, 1=K, 2=V (uniform per block)
#pragma unroll
  for (int ni = 0; ni < 4; ++ni) {
    const int col = n0 + wc * 64 + ni * 16 + lc;
    const int nn = col & 1023;
    const float bias = region == 0 ? bq[nn] : region == 1 ? bk[nn] : bvv[nn];
#pragma unroll
    for (int mi = 0; mi < 8; ++mi) {
      const int mBase = m0 + wr * 128 + mi * 16 + g * 4;
      if (region == 0) {
#pragma unroll
        for (int r = 0; r < 4; ++r)
          qout[(size_t)(mBase + r) * 1024 + nn] = f2bf(acc[mi][ni][r] + bias);
      } else if (region == 1) {
#pragma unroll
        for (int r = 0; r < 4; ++r)
          kout[(size_t)(mBase + r) * 1024 + nn] = f2bf(acc[mi][ni][r] + bias);
      } else {
        const int batch = mBase >> 9;
        const int s = mBase & 511;
        const int h = nn >> 6;
        const int d = nn & 63;
        ushort4 ov = make_ushort4(f2bf(acc[mi][ni][0] + bias), f2bf(acc[mi][ni][1] + bias),
                                  f2bf(acc[mi][ni][2] + bias), f2bf(acc[mi][ni][3] + bias));
        *(ushort4*)&vt[((size_t)((batch * 16 + h) * 64 + d) << 9) + s] = ov;
      }
    }
  }
}

// ---------------- O-projection GEMM (128x128 tile, unchanged) ----------------
__global__ __launch_bounds__(256, 2)
void gemm_out(const u16* __restrict__ A, const u16* __restrict__ W,
              const float* __restrict__ bias, float* __restrict__ outp) {
  __shared__ u16 Alds[128 * 32];
  __shared__ u16 Blds[128 * 32];
  const int tid  = threadIdx.x;
  const int lane = tid & 63;
  const int wid  = tid >> 6;
  const int orig = blockIdx.x;
  const int swz  = (orig & 7) * 64 + (orig >> 3);
  const int m0 = (swz >> 3) * 128;
  const int n0 = (swz & 7) * 128;
  const int wm = (wid >> 1) * 64;
  const int wn = (wid & 1) * 64;

  f32x4 acc[4][4] = {};

  const int srow = tid >> 2;
  const int scol = (tid & 3) * 8;
  const u16* Ag = A + (size_t)(m0 + srow) * 1024 + scol;
  const u16* Wg = W + (size_t)(n0 + srow) * 1024 + scol;
  u16* Al = &Alds[wid * 16 * 32];
  u16* Bl = &Blds[wid * 16 * 32];

  for (int k0 = 0; k0 < 1024; k0 += 32) {
    __syncthreads();
    gload_lds16(Ag + k0,             Al);
    gload_lds16(Ag + 64 * 1024 + k0, Al + 64 * 32);
    gload_lds16(Wg + k0,             Bl);
    gload_lds16(Wg + 64 * 1024 + k0, Bl + 64 * 32);
    __syncthreads();
    bf16x8 a[4], bb[4];
#pragma unroll
    for (int i = 0; i < 4; ++i)
      a[i] = *(const bf16x8*)&Alds[(wm + i * 16 + (lane & 15)) * 32 + (lane >> 4) * 8];
#pragma unroll
    for (int i = 0; i < 4; ++i)
      bb[i] = *(const bf16x8*)&Blds[(wn + i * 16 + (lane & 15)) * 32 + (lane >> 4) * 8];
#pragma unroll
    for (int mi = 0; mi < 4; ++mi)
#pragma unroll
      for (int ni = 0; ni < 4; ++ni)
        acc[mi][ni] = __builtin_amdgcn_mfma_f32_16x16x32_bf16(a[mi], bb[ni], acc[mi][ni], 0, 0, 0);
  }

#pragma unroll
  for (int ni = 0; ni < 4; ++ni) {
    const int n = n0 + wn + ni * 16 + (lane & 15);
    const float bv = bias[n];
#pragma unroll
    for (int mi = 0; mi < 4; ++mi) {
      const int mBase = m0 + wm + mi * 16 + ((lane >> 4) << 2);
#pragma unroll
      for (int r = 0; r < 4; ++r)
        outp[(size_t)(mBase + r) * 1024 + n] = acc[mi][ni][r] + bv;
    }
  }
}

// ---------------- attention (unchanged from round 4) ----------------
__global__ __launch_bounds__(256, 3)
void attn_kernel(const u16* __restrict__ Q, const u16* __restrict__ K,
                 const u16* __restrict__ Vt, const float* __restrict__ rel,
                 u16* __restrict__ Oa) {
  __shared__ u16 Kl[128 * 64];
  __shared__ u16 Vl[64 * 128];
  __shared__ u16 Pl[4][16 * 136];
  __shared__ float tcol[576];

  const int tid  = threadIdx.x;
  const int lane = tid & 63;
  const int wid  = tid >> 6;
  const int g    = lane >> 4;
  const int lc   = lane & 15;

  const int orig = blockIdx.x;
  const int swz  = (orig & 7) * 256 + (orig >> 3);
  const int qb    = swz & 7;
  const int bh    = swz >> 3;
  const int h     = bh & 15;
  const int batch = bh >> 4;
  const int q0    = qb * 64;

  const size_t xbase  = (size_t)batch * 512 * 1024 + (size_t)h * 64;
  const size_t vtbase = (size_t)(batch * 16 + h) * 64 * 512;

  for (int u = tid; u < 575; u += 256)
    tcol[u] = rel[(size_t)(q0 + u) * 16 + h];

#define STAGE_TILE(t)                                                              \
  {                                                                                \
    _Pragma("unroll")                                                              \
    for (int j = 0; j < 4; ++j) {                                                  \
      const int kr = j * 32 + (tid >> 3);                                          \
      const int sk = (tid & 7) ^ (kr & 7);                                         \
      gload_lds16(K + xbase + (size_t)((t) * 128 + kr) * 1024 + sk * 8,            \
                  &Kl[j * 2048 + wid * 512]);                                      \
      const int vr = j * 16 + (tid >> 4);                                          \
      const int sv = (tid & 15) ^ (vr & 7);                                        \
      gload_lds16(Vt + vtbase + (size_t)vr * 512 + (t) * 128 + sv * 8,             \
                  &Vl[j * 2048 + wid * 512]);                                      \
    }                                                                              \
  }

  STAGE_TILE(0)

  bf16x8 aq[2];
#pragma unroll
  for (int ks = 0; ks < 2; ++ks)
    aq[ks] = *(const bf16x8*)&Q[xbase + (size_t)(q0 + wid * 16 + lc) * 1024 + ks * 32 + g * 8];

  float m_run[4], l_run[4];
  f32x4 acc_o[4] = {};
#pragma unroll
  for (int r = 0; r < 4; ++r) { m_run[r] = -1e30f; l_run[r] = 0.f; }

  __syncthreads();

  const float scale = 0.125f;
  for (int t = 0; t < 4; ++t) {
    f32x4 acc[8] = {};
#pragma unroll
    for (int f = 0; f < 8; ++f) {
      const int rl = f * 16 + lc;
#pragma unroll
      for (int ks = 0; ks < 2; ++ks) {
        bf16x8 bk = *(const bf16x8*)&Kl[rl * 64 + (((ks * 4 + g) ^ (rl & 7)) * 8)];
        acc[f] = __builtin_amdgcn_mfma_f32_16x16x32_bf16(aq[ks], bk, acc[f], 0, 0, 0);
      }
    }
    const int ubase = wid * 16 + 4 * g + 511 - t * 128 - lc;
#pragma unroll
    for (int f = 0; f < 8; ++f)
#pragma unroll
      for (int r = 0; r < 4; ++r)
        acc[f][r] = acc[f][r] * scale + tcol[ubase + r - f * 16];

    float tm[4];
#pragma unroll
    for (int r = 0; r < 4; ++r) {
      float m = fmaxf(fmaxf(fmaxf(acc[0][r], acc[1][r]), fmaxf(acc[2][r], acc[3][r])),
                      fmaxf(fmaxf(acc[4][r], acc[5][r]), fmaxf(acc[6][r], acc[7][r])));
      m = fmaxf(m, __shfl_xor(m, 1));
      m = fmaxf(m, __shfl_xor(m, 2));
      m = fmaxf(m, __shfl_xor(m, 4));
      m = fmaxf(m, __shfl_xor(m, 8));
      tm[r] = m;
    }
    float al[4];
#pragma unroll
    for (int r = 0; r < 4; ++r) {
      const float mn = fmaxf(m_run[r], tm[r]);
      al[r] = __expf(m_run[r] - mn);
      m_run[r] = mn;
    }
    float ts[4] = {};
#pragma unroll
    for (int f = 0; f < 8; ++f)
#pragma unroll
      for (int r = 0; r < 4; ++r) {
        const float e = __expf(acc[f][r] - m_run[r]);
        ts[r] += e;
        Pl[wid][(4 * g + r) * 136 + f * 16 + lc] = f2bf(e);
      }
#pragma unroll
    for (int r = 0; r < 4; ++r) {
      float s = ts[r];
      s += __shfl_xor(s, 1);
      s += __shfl_xor(s, 2);
      s += __shfl_xor(s, 4);
      s += __shfl_xor(s, 8);
      l_run[r] = l_run[r] * al[r] + s;
    }
#pragma unroll
    for (int dblk = 0; dblk < 4; ++dblk)
#pragma unroll
      for (int r = 0; r < 4; ++r)
        acc_o[dblk][r] *= al[r];

#pragma unroll
    for (int ks = 0; ks < 4; ++ks) {
      bf16x8 ap = *(const bf16x8*)&Pl[wid][lc * 136 + ks * 32 + g * 8];
#pragma unroll
      for (int dblk = 0; dblk < 4; ++dblk) {
        const int dr = dblk * 16 + lc;
        bf16x8 bv = *(const bf16x8*)&Vl[dr * 128 + (((ks * 4 + g) ^ (dr & 7)) * 8)];
        acc_o[dblk] = __builtin_amdgcn_mfma_f32_16x16x32_bf16(ap, bv, acc_o[dblk], 0, 0, 0);
      }
    }

    if (t < 3) {
      __syncthreads();
      STAGE_TILE(t + 1)
      __syncthreads();
    }
  }
#undef STAGE_TILE

#pragma unroll
  for (int dblk = 0; dblk < 4; ++dblk)
#pragma unroll
    for (int r = 0; r < 4; ++r) {
      const int row = q0 + wid * 16 + 4 * g + r;
      Oa[((size_t)batch * 512 + row) * 1024 + h * 64 + dblk * 16 + lc] =
          f2bf(acc_o[dblk][r] / l_run[r]);
    }
}

// ---------------- launch ----------------
extern "C" void kernel_launch(void* const* d_in, const int* in_sizes, int n_in,
                              void* d_out, int out_size, void* d_ws, size_t ws_size,
                              hipStream_t stream) {
  (void)in_sizes; (void)n_in; (void)out_size; (void)ws_size;
  const float* x   = (const float*)d_in[0];
  const float* Wq  = (const float*)d_in[1];
  const float* bq  = (const float*)d_in[2];
  const float* Wk  = (const float*)d_in[3];
  const float* bk  = (const float*)d_in[4];
  const float* Wv  = (const float*)d_in[5];
  const float* bv  = (const float*)d_in[6];
  const float* Wo  = (const float*)d_in[7];
  const float* bo  = (const float*)d_in[8];
  const float* rel = (const float*)d_in[9];
  float* out = (float*)d_out;

  u16* p = (u16*)d_ws;
  u16* xbf = p;  p += (size_t)8192 * 1024;
  u16* wqb = p;  p += (size_t)1024 * 1024;   // wq, wk, wv contiguous => fused 3072x1024
  u16* wkb = p;  p += (size_t)1024 * 1024;
  u16* wvb = p;  p += (size_t)1024 * 1024;
  u16* wob = p;  p += (size_t)1024 * 1024;
  u16* qbf = p;  p += (size_t)8192 * 1024;
  u16* kbf = p;  p += (size_t)8192 * 1024;
  u16* vtb = p;  p += (size_t)8192 * 1024;
  u16* abf = p;  p += (size_t)8192 * 1024;

  cast_all_kernel<<<dim3(1024, 5), 256, 0, stream>>>(x, Wq, Wk, Wv, Wo,
                                                     xbf, wqb, wkb, wvb, wob);

  gemm_qkv8<<<384, 512, 0, stream>>>(xbf, wqb, bq, bk, bv, qbf, kbf, vtb);

  attn_kernel<<<2048, 256, 0, stream>>>(qbf, kbf, vtb, rel, abf);

  gemm_out<<<512, 256, 0, stream>>>(abf, wob, bo, out);
}

// Round 10
// 247.240 us; speedup vs baseline: 1.0069x; 1.0069x over previous
//
#include <hip/hip_runtime.h>
#include <cstdint>
#include <cstddef>

typedef unsigned short u16;
typedef __attribute__((ext_vector_type(8))) short bf16x8;   // 8 bf16 = 4 VGPRs
typedef __attribute__((ext_vector_type(4))) float f32x4;

__device__ __forceinline__ u16 f2bf(float f) {
  unsigned u = __builtin_bit_cast(unsigned, f);
  return (u16)((u + 0x7FFFu + ((u >> 16) & 1u)) >> 16);   // RNE
}

__device__ __forceinline__ void gload_lds16(const void* g, void* l) {
  __builtin_amdgcn_global_load_lds(
      (const __attribute__((address_space(1))) void*)g,
      (__attribute__((address_space(3))) void*)l,
      16, 0, 0);
}

// ---------------- merged cast fp32 -> bf16 (x + 4 weights, one launch) ----------------
__global__ void cast_all_kernel(const float* __restrict__ x,
                                const float* __restrict__ wq, const float* __restrict__ wk,
                                const float* __restrict__ wv, const float* __restrict__ wo,
                                u16* __restrict__ ox,
                                u16* __restrict__ oq, u16* __restrict__ ok,
                                u16* __restrict__ ov, u16* __restrict__ oo) {
  const int which = blockIdx.y;
  const float* in = which == 0 ? x  : which == 1 ? wq : which == 2 ? wk
                                    : which == 3 ? wv : wo;
  u16* out        = which == 0 ? ox : which == 1 ? oq : which == 2 ? ok
                                    : which == 3 ? ov : oo;
  const int n4 = which == 0 ? 8192 * 1024 / 4 : 262144;
  int i = blockIdx.x * blockDim.x + threadIdx.x;
  int stride = gridDim.x * blockDim.x;
  for (int idx = i; idx < n4; idx += stride) {
    float4 f = ((const float4*)in)[idx];
    ushort4 o = make_ushort4(f2bf(f.x), f2bf(f.y), f2bf(f.z), f2bf(f.w));
    ((ushort4*)out)[idx] = o;
  }
}

// ================= fused QKV GEMM, 8-phase 256x256 / BK=64 / 8-wave (frozen) =========
#define STAGE_A8(BUF, H, T)                                                    \
  { const u16* s_ = Asrc + (size_t)(H) * 131072 + (T) * 64;                    \
    u16* d_ = &lds[(BUF) * 32768 + (H) * 8192 + wid * 512];                    \
    gload_lds16(s_, d_);                                                       \
    gload_lds16(s_ + 65536, d_ + 4096); }

#define STAGE_B8(BUF, H, T)                                                    \
  { const u16* s_ = Wsrc + (size_t)(H) * 131072 + (T) * 64;                    \
    u16* d_ = &lds[(BUF) * 32768 + 16384 + (H) * 8192 + wid * 512];            \
    gload_lds16(s_, d_);                                                       \
    gload_lds16(s_ + 65536, d_ + 4096); }

#define LOAD_A8(BUF, MH)                                                       \
  _Pragma("unroll") for (int j_ = 0; j_ < 4; ++j_) {                           \
    const int r_ = ((MH) * 4 + j_) * 16 + lc;                                  \
    const int o_ = (BUF) * 32768 + abase + r_ * 64;                            \
    a[j_][0] = *(const bf16x8*)&lds[o_ + ((g ^ (r_ & 7)) * 8)];                \
    a[j_][1] = *(const bf16x8*)&lds[o_ + (((4 + g) ^ (r_ & 7)) * 8)];          \
  }

#define LOAD_B8(BUF, NH, BREG)                                                 \
  _Pragma("unroll") for (int j_ = 0; j_ < 2; ++j_) {                           \
    const int r_ = brlo + ((NH) * 2 + j_) * 16 + lc;                           \
    const int o_ = (BUF) * 32768 + bbase + r_ * 64;                            \
    BREG[j_][0] = *(const bf16x8*)&lds[o_ + ((g ^ (r_ & 7)) * 8)];             \
    BREG[j_][1] = *(const bf16x8*)&lds[o_ + (((4 + g) ^ (r_ & 7)) * 8)];       \
  }

#define MMAQ8(MH, NH, BREG)                                                    \
  __builtin_amdgcn_s_setprio(1);                                               \
  _Pragma("unroll") for (int j_ = 0; j_ < 4; ++j_)                             \
    _Pragma("unroll") for (int n_ = 0; n_ < 2; ++n_) {                         \
      acc[(MH) * 4 + j_][(NH) * 2 + n_] =                                      \
          __builtin_amdgcn_mfma_f32_16x16x32_bf16(                             \
              a[j_][0], BREG[n_][0], acc[(MH) * 4 + j_][(NH) * 2 + n_], 0, 0, 0); \
      acc[(MH) * 4 + j_][(NH) * 2 + n_] =                                      \
          __builtin_amdgcn_mfma_f32_16x16x32_bf16(                             \
              a[j_][1], BREG[n_][1], acc[(MH) * 4 + j_][(NH) * 2 + n_], 0, 0, 0); \
    }                                                                          \
  __builtin_amdgcn_s_setprio(0);

#define BAR1a                                                                  \
  __builtin_amdgcn_s_barrier();                                                \
  asm volatile("s_waitcnt lgkmcnt(0)" ::: "memory");                           \
  __builtin_amdgcn_sched_barrier(0);

#define BAR2a __builtin_amdgcn_s_barrier();

#define VMW(N) asm volatile("s_waitcnt vmcnt(" #N ")" ::: "memory");

__global__ __launch_bounds__(512, 2)
void gemm_qkv8(const u16* __restrict__ A, const u16* __restrict__ W,
               const float* __restrict__ bq, const float* __restrict__ bk,
               const float* __restrict__ bvv,
               u16* __restrict__ qout, u16* __restrict__ kout, u16* __restrict__ vt) {
  __shared__ u16 lds[65536];   // 128 KiB
  const int tid  = threadIdx.x;
  const int lane = tid & 63;
  const int wid  = tid >> 6;       // 0..7
  const int wr   = wid >> 2;       // 0..1 : which 128-row half of C
  const int wc   = wid & 3;        // 0..3 : which 64-col strip of C
  const int lc   = lane & 15;
  const int g    = lane >> 4;

  const int orig = blockIdx.x;
  const int swz  = (orig & 7) * 48 + (orig >> 3);
  const int m0 = (swz / 12) * 256;
  const int n0 = (swz % 12) * 256;

  const int srow  = tid >> 3;                         // 0..63
  const int scol8 = ((tid & 7) ^ (srow & 7)) * 8;     // inverse-swizzled source col
  const u16* Asrc = A + (size_t)(m0 + srow) * 1024 + scol8;
  const u16* Wsrc = W + (size_t)(n0 + srow) * 1024 + scol8;

  const int abase = wr * 8192;
  const int bbase = 16384 + (wc >> 1) * 8192;
  const int brlo  = (wc & 1) * 64;

  f32x4 acc[8][4] = {};
  bf16x8 a[4][2], bA[2][2], bB[2][2];

  STAGE_B8(0, 0, 0) STAGE_B8(0, 1, 0) STAGE_A8(0, 0, 0) STAGE_A8(0, 1, 0)
  STAGE_B8(1, 0, 1) STAGE_B8(1, 1, 1)
  VMW(4)
  __builtin_amdgcn_s_barrier();

  for (int i = 0; i < 7; ++i) {
    const int tb  = 2 * i + 1;
    const int ta2 = 2 * i + 2;
    const int tb2 = 2 * i + 3;
    LOAD_A8(0, 0) LOAD_B8(0, 0, bA) STAGE_A8(1, 0, tb) BAR1a MMAQ8(0, 0, bA) BAR2a
    LOAD_B8(0, 1, bB) STAGE_A8(1, 1, tb) BAR1a MMAQ8(0, 1, bB) BAR2a
    LOAD_A8(0, 1) STAGE_B8(0, 0, ta2) BAR1a MMAQ8(1, 0, bA) BAR2a
    STAGE_B8(0, 1, ta2) BAR1a MMAQ8(1, 1, bB) VMW(4) BAR2a
    LOAD_A8(1, 0) LOAD_B8(1, 0, bA) STAGE_A8(0, 0, ta2) BAR1a MMAQ8(0, 0, bA) BAR2a
    LOAD_B8(1, 1, bB) STAGE_A8(0, 1, ta2) BAR1a MMAQ8(0, 1, bB) BAR2a
    LOAD_A8(1, 1) STAGE_B8(1, 0, tb2) BAR1a MMAQ8(1, 0, bA) BAR2a
    STAGE_B8(1, 1, tb2) BAR1a MMAQ8(1, 1, bB) VMW(4) BAR2a
  }
  LOAD_A8(0, 0) LOAD_B8(0, 0, bA) STAGE_A8(1, 0, 15) BAR1a MMAQ8(0, 0, bA) BAR2a
  LOAD_B8(0, 1, bB) STAGE_A8(1, 1, 15) BAR1a MMAQ8(0, 1, bB) BAR2a
  LOAD_A8(0, 1) BAR1a MMAQ8(1, 0, bA) BAR2a
  BAR1a MMAQ8(1, 1, bB) VMW(0) BAR2a
  LOAD_A8(1, 0) LOAD_B8(1, 0, bA) BAR1a MMAQ8(0, 0, bA) BAR2a
  LOAD_B8(1, 1, bB) BAR1a MMAQ8(0, 1, bB) BAR2a
  LOAD_A8(1, 1) BAR1a MMAQ8(1, 0, bA) BAR2a
  BAR1a MMAQ8(1, 1, bB)

  const int region = n0 >> 10;   // 0=Q, 1=K, 2=V (uniform per block)
#pragma unroll
  for (int ni = 0; ni < 4; ++ni) {
    const int col = n0 + wc * 64 + ni * 16 + lc;
    const int nn = col & 1023;
    const float bias = region == 0 ? bq[nn] : region == 1 ? bk[nn] : bvv[nn];
#pragma unroll
    for (int mi = 0; mi < 8; ++mi) {
      const int mBase = m0 + wr * 128 + mi * 16 + g * 4;
      if (region == 0) {
#pragma unroll
        for (int r = 0; r < 4; ++r)
          qout[(size_t)(mBase + r) * 1024 + nn] = f2bf(acc[mi][ni][r] + bias);
      } else if (region == 1) {
#pragma unroll
        for (int r = 0; r < 4; ++r)
          kout[(size_t)(mBase + r) * 1024 + nn] = f2bf(acc[mi][ni][r] + bias);
      } else {
        const int batch = mBase >> 9;
        const int s = mBase & 511;
        const int h = nn >> 6;
        const int d = nn & 63;
        ushort4 ov = make_ushort4(f2bf(acc[mi][ni][0] + bias), f2bf(acc[mi][ni][1] + bias),
                                  f2bf(acc[mi][ni][2] + bias), f2bf(acc[mi][ni][3] + bias));
        *(ushort4*)&vt[((size_t)((batch * 16 + h) * 64 + d) << 9) + s] = ov;
      }
    }
  }
}

// ---------------- O-projection GEMM (128x128 tile, unchanged) ----------------
__global__ __launch_bounds__(256, 2)
void gemm_out(const u16* __restrict__ A, const u16* __restrict__ W,
              const float* __restrict__ bias, float* __restrict__ outp) {
  __shared__ u16 Alds[128 * 32];
  __shared__ u16 Blds[128 * 32];
  const int tid  = threadIdx.x;
  const int lane = tid & 63;
  const int wid  = tid >> 6;
  const int orig = blockIdx.x;
  const int swz  = (orig & 7) * 64 + (orig >> 3);
  const int m0 = (swz >> 3) * 128;
  const int n0 = (swz & 7) * 128;
  const int wm = (wid >> 1) * 64;
  const int wn = (wid & 1) * 64;

  f32x4 acc[4][4] = {};

  const int srow = tid >> 2;
  const int scol = (tid & 3) * 8;
  const u16* Ag = A + (size_t)(m0 + srow) * 1024 + scol;
  const u16* Wg = W + (size_t)(n0 + srow) * 1024 + scol;
  u16* Al = &Alds[wid * 16 * 32];
  u16* Bl = &Blds[wid * 16 * 32];

  for (int k0 = 0; k0 < 1024; k0 += 32) {
    __syncthreads();
    gload_lds16(Ag + k0,             Al);
    gload_lds16(Ag + 64 * 1024 + k0, Al + 64 * 32);
    gload_lds16(Wg + k0,             Bl);
    gload_lds16(Wg + 64 * 1024 + k0, Bl + 64 * 32);
    __syncthreads();
    bf16x8 a[4], bb[4];
#pragma unroll
    for (int i = 0; i < 4; ++i)
      a[i] = *(const bf16x8*)&Alds[(wm + i * 16 + (lane & 15)) * 32 + (lane >> 4) * 8];
#pragma unroll
    for (int i = 0; i < 4; ++i)
      bb[i] = *(const bf16x8*)&Blds[(wn + i * 16 + (lane & 15)) * 32 + (lane >> 4) * 8];
#pragma unroll
    for (int mi = 0; mi < 4; ++mi)
#pragma unroll
      for (int ni = 0; ni < 4; ++ni)
        acc[mi][ni] = __builtin_amdgcn_mfma_f32_16x16x32_bf16(a[mi], bb[ni], acc[mi][ni], 0, 0, 0);
  }

#pragma unroll
  for (int ni = 0; ni < 4; ++ni) {
    const int n = n0 + wn + ni * 16 + (lane & 15);
    const float bv = bias[n];
#pragma unroll
    for (int mi = 0; mi < 4; ++mi) {
      const int mBase = m0 + wm + mi * 16 + ((lane >> 4) << 2);
#pragma unroll
      for (int r = 0; r < 4; ++r)
        outp[(size_t)(mBase + r) * 1024 + n] = acc[mi][ni][r] + bv;
    }
  }
}

// ---------------- attention: one block per (b,h,qblock of 128 rows) ----------------
// 4 waves x 32 q-rows each; online softmax in-register with defer-max (T13);
// K/V 128-key tiles staged in LDS (XOR-pre-swizzled source); setprio around MFMA (T5).
__global__ __launch_bounds__(256, 2)
void attn_kernel(const u16* __restrict__ Q, const u16* __restrict__ K,
                 const u16* __restrict__ Vt, const float* __restrict__ rel,
                 u16* __restrict__ Oa) {
  __shared__ u16 Kl[128 * 64];        // 16 KB: row=key, 64 d (XOR-swz)
  __shared__ u16 Vl[64 * 128];        // 16 KB: row=d, 128 keys (XOR-swz)
  __shared__ u16 Pl[4][32 * 136];     // 34.8 KB: per-wave P (32 rows, stride 136)
  __shared__ float tcol[640];         // rel-bias slice

  const int tid  = threadIdx.x;
  const int lane = tid & 63;
  const int wid  = tid >> 6;
  const int g    = lane >> 4;         // 0..3
  const int lc   = lane & 15;

  // XCD swizzle: 1024 wgs = 8 XCDs x 128; q-blocks of one (b,h) contiguous per XCD
  const int orig = blockIdx.x;
  const int swz  = (orig & 7) * 128 + (orig >> 3);
  const int qb    = swz & 3;
  const int bh    = swz >> 2;
  const int h     = bh & 15;
  const int batch = bh >> 4;
  const int q0    = qb * 128;

  const size_t xbase  = (size_t)batch * 512 * 1024 + (size_t)h * 64;
  const size_t vtbase = (size_t)(batch * 16 + h) * 64 * 512;

  // bias(rowl,col) = tcol[rowl - col + 511], rowl in [0,128), col in [0,512)
  for (int u = tid; u < 639; u += 256)
    tcol[u] = rel[(size_t)(q0 + u) * 16 + h];

#define STAGE_TILE(t)                                                              \
  {                                                                                \
    _Pragma("unroll")                                                              \
    for (int j = 0; j < 4; ++j) {                                                  \
      const int kr = j * 32 + (tid >> 3);                                          \
      const int sk = (tid & 7) ^ (kr & 7);                                         \
      gload_lds16(K + xbase + (size_t)((t) * 128 + kr) * 1024 + sk * 8,            \
                  &Kl[j * 2048 + wid * 512]);                                      \
      const int vr = j * 16 + (tid >> 4);                                          \
      const int sv = (tid & 15) ^ (vr & 7);                                        \
      gload_lds16(Vt + vtbase + (size_t)vr * 512 + (t) * 128 + sv * 8,             \
                  &Vl[j * 2048 + wid * 512]);                                      \
    }                                                                              \
  }

  STAGE_TILE(0)

  // Q fragments: wave owns rows q0 + wid*32 + [0,32)  (two 16-row tiles)
  bf16x8 aq[2][2];
#pragma unroll
  for (int mi = 0; mi < 2; ++mi)
#pragma unroll
    for (int ks = 0; ks < 2; ++ks)
      aq[mi][ks] = *(const bf16x8*)&Q[xbase + (size_t)(q0 + wid * 32 + mi * 16 + lc) * 1024 +
                                      ks * 32 + g * 8];

  float m_run[2][4], l_run[2][4];
  f32x4 acc_o[2][4] = {};
#pragma unroll
  for (int mi = 0; mi < 2; ++mi)
#pragma unroll
    for (int r = 0; r < 4; ++r) { m_run[mi][r] = -1e30f; l_run[mi][r] = 0.f; }

  __syncthreads();   // tile 0 + tcol ready

  const float scale = 0.125f;  // 1/sqrt(64)
  for (int t = 0; t < 4; ++t) {
    // ---- QK^T on 128-key tile ----
    f32x4 acc[2][8] = {};
    __builtin_amdgcn_s_setprio(1);
#pragma unroll
    for (int f = 0; f < 8; ++f) {
      const int rl = f * 16 + lc;
#pragma unroll
      for (int ks = 0; ks < 2; ++ks) {
        bf16x8 bk = *(const bf16x8*)&Kl[rl * 64 + (((ks * 4 + g) ^ (rl & 7)) * 8)];
#pragma unroll
        for (int mi = 0; mi < 2; ++mi)
          acc[mi][f] = __builtin_amdgcn_mfma_f32_16x16x32_bf16(aq[mi][ks], bk, acc[mi][f], 0, 0, 0);
      }
    }
    __builtin_amdgcn_s_setprio(0);

    // ---- scale + rel bias (rowl = wid*32 + mi*16 + 4g + r, col = t*128 + f*16 + lc)
#pragma unroll
    for (int mi = 0; mi < 2; ++mi) {
      const int ub = wid * 32 + mi * 16 + 4 * g + 511 - t * 128 - lc;
#pragma unroll
      for (int f = 0; f < 8; ++f)
#pragma unroll
        for (int r = 0; r < 4; ++r)
          acc[mi][f][r] = acc[mi][f][r] * scale + tcol[ub + r - f * 16];
    }

    // ---- tile max per row ----
    float tm[2][4];
#pragma unroll
    for (int mi = 0; mi < 2; ++mi)
#pragma unroll
      for (int r = 0; r < 4; ++r) {
        float m = fmaxf(fmaxf(fmaxf(acc[mi][0][r], acc[mi][1][r]),
                              fmaxf(acc[mi][2][r], acc[mi][3][r])),
                        fmaxf(fmaxf(acc[mi][4][r], acc[mi][5][r]),
                              fmaxf(acc[mi][6][r], acc[mi][7][r])));
        m = fmaxf(m, __shfl_xor(m, 1));
        m = fmaxf(m, __shfl_xor(m, 2));
        m = fmaxf(m, __shfl_xor(m, 4));
        m = fmaxf(m, __shfl_xor(m, 8));
        tm[mi][r] = m;
      }

    // ---- defer-max (T13): rescale only if some row grew by > 8 ----
    bool need = false;
#pragma unroll
    for (int mi = 0; mi < 2; ++mi)
#pragma unroll
      for (int r = 0; r < 4; ++r)
        need = need || (tm[mi][r] - m_run[mi][r] > 8.0f);
    if (__ballot(need) != 0ull) {
#pragma unroll
      for (int mi = 0; mi < 2; ++mi)
#pragma unroll
        for (int r = 0; r < 4; ++r) {
          const float mn = fmaxf(m_run[mi][r], tm[mi][r]);
          const float al = __expf(m_run[mi][r] - mn);
          m_run[mi][r] = mn;
          l_run[mi][r] *= al;
#pragma unroll
          for (int dblk = 0; dblk < 4; ++dblk)
            acc_o[mi][dblk][r] *= al;
        }
    }

    // ---- exp + P(bf16) + row sums ----
    float ts[2][4] = {};
#pragma unroll
    for (int mi = 0; mi < 2; ++mi)
#pragma unroll
      for (int f = 0; f < 8; ++f)
#pragma unroll
        for (int r = 0; r < 4; ++r) {
          const float e = __expf(acc[mi][f][r] - m_run[mi][r]);
          ts[mi][r] += e;
          Pl[wid][(mi * 16 + 4 * g + r) * 136 + f * 16 + lc] = f2bf(e);
        }
#pragma unroll
    for (int mi = 0; mi < 2; ++mi)
#pragma unroll
      for (int r = 0; r < 4; ++r) {
        float s = ts[mi][r];
        s += __shfl_xor(s, 1);
        s += __shfl_xor(s, 2);
        s += __shfl_xor(s, 4);
        s += __shfl_xor(s, 8);
        l_run[mi][r] += s;
      }

    // ---- PV ----
    __builtin_amdgcn_s_setprio(1);
#pragma unroll
    for (int ks = 0; ks < 4; ++ks) {
      bf16x8 ap0 = *(const bf16x8*)&Pl[wid][(lc) * 136 + ks * 32 + g * 8];
      bf16x8 ap1 = *(const bf16x8*)&Pl[wid][(16 + lc) * 136 + ks * 32 + g * 8];
#pragma unroll
      for (int dblk = 0; dblk < 4; ++dblk) {
        const int dr = dblk * 16 + lc;
        bf16x8 bv = *(const bf16x8*)&Vl[dr * 128 + (((ks * 4 + g) ^ (dr & 7)) * 8)];
        acc_o[0][dblk] = __builtin_amdgcn_mfma_f32_16x16x32_bf16(ap0, bv, acc_o[0][dblk], 0, 0, 0);
        acc_o[1][dblk] = __builtin_amdgcn_mfma_f32_16x16x32_bf16(ap1, bv, acc_o[1][dblk], 0, 0, 0);
      }
    }
    __builtin_amdgcn_s_setprio(0);

    if (t < 3) {
      __syncthreads();
      STAGE_TILE(t + 1)
      __syncthreads();
    }
  }
#undef STAGE_TILE

  // ---- epilogue ----
#pragma unroll
  for (int mi = 0; mi < 2; ++mi)
#pragma unroll
    for (int dblk = 0; dblk < 4; ++dblk)
#pragma unroll
      for (int r = 0; r < 4; ++r) {
        const int row = q0 + wid * 32 + mi * 16 + 4 * g + r;
        Oa[((size_t)batch * 512 + row) * 1024 + h * 64 + dblk * 16 + lc] =
            f2bf(acc_o[mi][dblk][r] / l_run[mi][r]);
      }
}

// ---------------- launch ----------------
extern "C" void kernel_launch(void* const* d_in, const int* in_sizes, int n_in,
                              void* d_out, int out_size, void* d_ws, size_t ws_size,
                              hipStream_t stream) {
  (void)in_sizes; (void)n_in; (void)out_size; (void)ws_size;
  const float* x   = (const float*)d_in[0];
  const float* Wq  = (const float*)d_in[1];
  const float* bq  = (const float*)d_in[2];
  const float* Wk  = (const float*)d_in[3];
  const float* bk  = (const float*)d_in[4];
  const float* Wv  = (const float*)d_in[5];
  const float* bv  = (const float*)d_in[6];
  const float* Wo  = (const float*)d_in[7];
  const float* bo  = (const float*)d_in[8];
  const float* rel = (const float*)d_in[9];
  float* out = (float*)d_out;

  u16* p = (u16*)d_ws;
  u16* xbf = p;  p += (size_t)8192 * 1024;
  u16* wqb = p;  p += (size_t)1024 * 1024;   // wq, wk, wv contiguous => fused 3072x1024
  u16* wkb = p;  p += (size_t)1024 * 1024;
  u16* wvb = p;  p += (size_t)1024 * 1024;
  u16* wob = p;  p += (size_t)1024 * 1024;
  u16* qbf = p;  p += (size_t)8192 * 1024;
  u16* kbf = p;  p += (size_t)8192 * 1024;
  u16* vtb = p;  p += (size_t)8192 * 1024;
  u16* abf = p;  p += (size_t)8192 * 1024;

  cast_all_kernel<<<dim3(1024, 5), 256, 0, stream>>>(x, Wq, Wk, Wv, Wo,
                                                     xbf, wqb, wkb, wvb, wob);

  gemm_qkv8<<<384, 512, 0, stream>>>(xbf, wqb, bq, bk, bv, qbf, kbf, vtb);

  attn_kernel<<<1024, 256, 0, stream>>>(qbf, kbf, vtb, rel, abf);

  gemm_out<<<512, 256, 0, stream>>>(abf, wob, bo, out);
}